// Round 7
// baseline (157.531 us; speedup 1.0000x reference)
//
#include <hip/hip_runtime.h>
#include <hip/hip_bf16.h>
#include <math.h>

#define B 8
#define N 2048
#define F_IN 128
#define F_OUT 64
#define ALPHA 0.2f

typedef _Float16 half8 __attribute__((ext_vector_type(8)));
typedef float f32x4 __attribute__((ext_vector_type(4)));

// ---------------------------------------------------------------------------
// Kernel 1: adj -> bitmask
// ---------------------------------------------------------------------------
__global__ __launch_bounds__(256) void bitmask_kernel(
    const float* __restrict__ adj, unsigned* __restrict__ bits)
{
    const int i = blockIdx.x;
    const int tid = threadIdx.x;
    const int lane = tid & 63;
    const int w = tid >> 6;
    const float* row = adj + (size_t)i * N;
#pragma unroll
    for (int jt = 0; jt < 8; ++jt) {
        float v = row[jt * 256 + tid];
        unsigned long long m = __ballot(v > 0.f);
        if (lane == 0) {
            bits[i * 64 + jt * 8 + w * 2]     = (unsigned)m;
            bits[i * 64 + jt * 8 + w * 2 + 1] = (unsigned)(m >> 32);
        }
    }
}

// ---------------------------------------------------------------------------
// Kernel 2: WhT[b][f][j] (f16) = (h @ W)^T, f = Wh.a1, g = Wh.a2 (fp32)
// ---------------------------------------------------------------------------
__global__ __launch_bounds__(256) void wh_fg_t_kernel(
    const float* __restrict__ h, const float* __restrict__ W,
    const float* __restrict__ a, _Float16* __restrict__ WhT,
    float* __restrict__ fv, float* __restrict__ gv)
{
    const int tid  = threadIdx.x;
    const int w    = tid >> 6;
    const int lane = tid & 63;

    __shared__ float Ws[F_IN * F_OUT];
    __shared__ float hs[16 * F_IN];
    __shared__ float t32[16 * 65];

    const float4* W4 = (const float4*)W;
    float4* Ws4 = (float4*)Ws;
#pragma unroll
    for (int q = 0; q < 8; ++q)
        Ws4[q * 256 + tid] = W4[q * 256 + tid];

    const float4* h4 = (const float4*)h;
    float4* hs4 = (float4*)hs;
    const size_t hbase = (size_t)blockIdx.x * 512;
#pragma unroll
    for (int q = 0; q < 2; ++q)
        hs4[q * 256 + tid] = h4[hbase + q * 256 + tid];

    const float av1 = a[lane];
    const float av2 = a[F_OUT + lane];
    __syncthreads();

    float acc[4] = {0.f, 0.f, 0.f, 0.f};
    const int lr0 = w * 4;
    for (int k4 = 0; k4 < F_IN / 4; ++k4) {
        float4 hv[4];
#pragma unroll
        for (int rr = 0; rr < 4; ++rr)
            hv[rr] = hs4[(lr0 + rr) * (F_IN / 4) + k4];
#pragma unroll
        for (int kk = 0; kk < 4; ++kk) {
            float wv = Ws[(k4 * 4 + kk) * F_OUT + lane];
#pragma unroll
            for (int rr = 0; rr < 4; ++rr)
                acc[rr] += ((const float*)&hv[rr])[kk] * wv;
        }
    }

    const int b     = blockIdx.x >> 7;
    const int j0    = (blockIdx.x & 127) * 16;
    const size_t gr0 = (size_t)b * N + j0 + lr0;

#pragma unroll
    for (int rr = 0; rr < 4; ++rr) {
        t32[(lr0 + rr) * 65 + lane] = acc[rr];
        float fp = acc[rr] * av1;
        float gp = acc[rr] * av2;
#pragma unroll
        for (int off = 32; off >= 1; off >>= 1) {
            fp += __shfl_down(fp, off, 64);
            gp += __shfl_down(gp, off, 64);
        }
        if (lane == 0) {
            fv[gr0 + rr] = fp;
            gv[gr0 + rr] = gp;
        }
    }
    __syncthreads();

    const int f  = tid >> 2;
    const int jq = tid & 3;
    union { _Float16 h[4]; ushort4 u; } pk;
#pragma unroll
    for (int t = 0; t < 4; ++t)
        pk.h[t] = (_Float16)t32[(jq * 4 + t) * 65 + f];
    *(ushort4*)(WhT + (size_t)b * F_OUT * N + (size_t)f * N + j0 + jq * 4) = pk.u;
}

// ---------------------------------------------------------------------------
// Kernel 3: MFMA aggregation, per-wave-private P (A-fragment generated in
// registers). Block = 64 i's (wave w owns i-tile w), shared 64x128 WhT slab.
// 16 MFMA + 32 scores per wave per barrier pair; slab global loads
// register-prefetched one round ahead.
// ---------------------------------------------------------------------------
#define PSTR 136   // slab row stride in f16 (272 B)

__global__ __launch_bounds__(256) void attn_mfma_kernel(
    const _Float16* __restrict__ WhT, const float* __restrict__ fv,
    const float* __restrict__ gv, const unsigned* __restrict__ bits,
    float* __restrict__ out)
{
    const int i0 = blockIdx.x * 64;
    const int b  = blockIdx.y;
    const int tid  = threadIdx.x;
    const int lane = tid & 63;
    const int w    = tid >> 6;

    __shared__ float    gs[N];            // 8 KB
    __shared__ float    fs[64], ms[64];
    __shared__ unsigned mws[64 * 65];     // 16.6 KB, padded stride 65
    __shared__ _Float16 slab[64 * PSTR];  // 17 KB

    // stage g, f, mask words
    const float4* g4 = (const float4*)(gv + (size_t)b * N);
    ((float4*)gs)[tid]       = g4[tid];
    ((float4*)gs)[tid + 256] = g4[tid + 256];
    if (tid < 64) fs[tid] = fv[(size_t)b * N + i0 + tid];
    {
        const unsigned* bsrc = bits + (size_t)i0 * 64;
#pragma unroll
        for (int t = 0; t < 16; ++t) {
            int idx = t * 256 + tid;        // 0..4095
            mws[(idx >> 6) * 65 + (idx & 63)] = bsrc[idx];
        }
    }
    __syncthreads();

    // per-row masked max of g: 4 threads per row
    {
        const int row  = tid >> 2;
        const int part = tid & 3;
        float gm = -INFINITY;
#pragma unroll
        for (int t = 0; t < 16; ++t) {
            unsigned mw = mws[row * 65 + part * 16 + t];
            const int jb = part * 512 + t * 32;
            while (mw) {
                int bit = __builtin_ctz(mw);
                gm = fmaxf(gm, gs[jb + bit]);
                mw &= mw - 1;
            }
        }
        gm = fmaxf(gm, __shfl_down(gm, 2, 4));
        gm = fmaxf(gm, __shfl_down(gm, 1, 4));
        if (part == 0) {
            float m = fs[row] + gm;         // leaky monotone
            ms[row] = (m > 0.f) ? m : ALPHA * m;
        }
    }
    __syncthreads();

    const int mrow = lane & 15;
    const int quad = lane >> 4;
    const int lrow = w * 16 + mrow;         // block-local i row of this lane
    const float fi = fs[lrow];
    const float mi = ms[lrow];

    // slab staging coords: thread stages feature row tid>>2, 64 B segment tid&3
    const int srow = tid >> 2;
    const int seg  = tid & 3;
    const _Float16* gsrc = WhT + ((size_t)b * F_OUT + srow) * N + seg * 32;

    f32x4 acc[4] = {{0.f,0.f,0.f,0.f},{0.f,0.f,0.f,0.f},
                    {0.f,0.f,0.f,0.f},{0.f,0.f,0.f,0.f}};
    float psum = 0.f;

    // prefetch round 0
    float4 r[4];
#pragma unroll
    for (int q = 0; q < 4; ++q)
        r[q] = *(const float4*)(gsrc + q * 8);

    for (int kt = 0; kt < N / 128; ++kt) {
        const int j0 = kt * 128;
        __syncthreads();    // previous slab fully consumed
#pragma unroll
        for (int q = 0; q < 4; ++q)
            *(float4*)(&slab[srow * PSTR + seg * 32 + q * 8]) = r[q];
        __syncthreads();    // slab ready
        if (kt < N / 128 - 1) {
#pragma unroll
            for (int q = 0; q < 4; ++q)
                r[q] = *(const float4*)(gsrc + j0 + 128 + q * 8);
        }

#pragma unroll
        for (int q = 0; q < 4; ++q) {
            const int kbase = j0 + q * 32 + quad * 8;
            unsigned mb = (mws[lrow * 65 + (j0 >> 5) + q] >> (quad * 8)) & 0xFFu;
            union { float4 v[2]; float s[8]; } gg;
            gg.v[0] = *(const float4*)(&gs[kbase]);
            gg.v[1] = *(const float4*)(&gs[kbase + 4]);
            half8 aF;
#pragma unroll
            for (int t = 0; t < 8; ++t) {
                float s = fi + gg.s[t];
                s = (s > 0.f) ? s : ALPHA * s;
                float p = ((mb >> t) & 1u) ? __expf(s - mi) : 0.f;
                aF[t] = (_Float16)p;
                psum += (float)aF[t];
            }
#pragma unroll
            for (int fg = 0; fg < 4; ++fg) {
                half8 bF = *(const half8*)(&slab[(fg * 16 + mrow) * PSTR + q * 32 + quad * 8]);
                acc[fg] = __builtin_amdgcn_mfma_f32_16x16x32_f16(aF, bF, acc[fg], 0, 0, 0);
            }
        }
    }

    // denominator: lanes {m, m+16, m+32, m+48} hold disjoint k-partials of row m
    psum += __shfl_down(psum, 32, 64);
    psum += __shfl_down(psum, 16, 64);     // lanes 0..15 = row totals
    float dinv[4];
#pragma unroll
    for (int reg = 0; reg < 4; ++reg)
        dinv[reg] = 1.0f / __shfl(psum, quad * 4 + reg, 64);

    // epilogue: C/D layout row = quad*4+reg, col = mrow (feature fg*16+mrow)
#pragma unroll
    for (int fg = 0; fg < 4; ++fg)
#pragma unroll
        for (int reg = 0; reg < 4; ++reg) {
            int irow = i0 + w * 16 + quad * 4 + reg;
            out[((size_t)b * N + irow) * F_OUT + fg * 16 + mrow] = acc[fg][reg] * dinv[reg];
        }
}

extern "C" void kernel_launch(void* const* d_in, const int* in_sizes, int n_in,
                              void* d_out, int out_size, void* d_ws, size_t ws_size,
                              hipStream_t stream) {
    const float* h   = (const float*)d_in[0];
    const float* adj = (const float*)d_in[1];
    const float* W   = (const float*)d_in[2];
    const float* a   = (const float*)d_in[3];
    float* out = (float*)d_out;

    char* ws = (char*)d_ws;
    _Float16* WhT = (_Float16*)ws;                        // 2 MB
    float* fv = (float*)(ws + (size_t)B * F_OUT * N * 2); // 64 KB
    float* gv = fv + (size_t)B * N;                       // 64 KB
    unsigned* bits = (unsigned*)(gv + (size_t)B * N);     // 512 KB

    bitmask_kernel<<<dim3(N), 256, 0, stream>>>(adj, bits);
    wh_fg_t_kernel<<<dim3(B * N / 16), 256, 0, stream>>>(h, W, a, WhT, fv, gv);
    attn_mfma_kernel<<<dim3(N / 64, B), 256, 0, stream>>>(WhT, fv, gv, bits, out);
}

// Round 9
// 146.373 us; speedup vs baseline: 1.0762x; 1.0762x over previous
//
#include <hip/hip_runtime.h>
#include <hip/hip_bf16.h>
#include <math.h>

#define B 8
#define N 2048
#define F_IN 128
#define F_OUT 64
#define ALPHA 0.2f

typedef _Float16 half8 __attribute__((ext_vector_type(8)));
typedef float f32x4 __attribute__((ext_vector_type(4)));

// ---------------------------------------------------------------------------
// Kernel 1: adj -> bitmask (u32 words). bits[i*64 + j/32] bit (j%32) = adj[i][j]>0
// ---------------------------------------------------------------------------
__global__ __launch_bounds__(256) void bitmask_kernel(
    const float* __restrict__ adj, unsigned* __restrict__ bits)
{
    const int i = blockIdx.x;
    const int tid = threadIdx.x;
    const int lane = tid & 63;
    const int w = tid >> 6;
    const float* row = adj + (size_t)i * N;
#pragma unroll
    for (int jt = 0; jt < 8; ++jt) {
        float v = row[jt * 256 + tid];
        unsigned long long m = __ballot(v > 0.f);
        if (lane == 0) {
            bits[i * 64 + jt * 8 + w * 2]     = (unsigned)m;
            bits[i * 64 + jt * 8 + w * 2 + 1] = (unsigned)(m >> 32);
        }
    }
}

// ---------------------------------------------------------------------------
// Kernel 2: WhT[b][f][j] (f16) = (h @ W)^T, plus f = Wh.a1, g = Wh.a2 (fp32)
// ---------------------------------------------------------------------------
__global__ __launch_bounds__(256) void wh_fg_t_kernel(
    const float* __restrict__ h, const float* __restrict__ W,
    const float* __restrict__ a, _Float16* __restrict__ WhT,
    float* __restrict__ fv, float* __restrict__ gv)
{
    const int tid  = threadIdx.x;
    const int w    = tid >> 6;
    const int lane = tid & 63;

    __shared__ float Ws[F_IN * F_OUT];    // 32 KB
    __shared__ float hs[16 * F_IN];       // 8 KB
    __shared__ float t32[16 * 65];        // transpose buffer (pad 65)

    const float4* W4 = (const float4*)W;
    float4* Ws4 = (float4*)Ws;
#pragma unroll
    for (int q = 0; q < 8; ++q)
        Ws4[q * 256 + tid] = W4[q * 256 + tid];

    const float4* h4 = (const float4*)h;
    float4* hs4 = (float4*)hs;
    const size_t hbase = (size_t)blockIdx.x * 512;
#pragma unroll
    for (int q = 0; q < 2; ++q)
        hs4[q * 256 + tid] = h4[hbase + q * 256 + tid];

    const float av1 = a[lane];
    const float av2 = a[F_OUT + lane];
    __syncthreads();

    float acc[4] = {0.f, 0.f, 0.f, 0.f};
    const int lr0 = w * 4;
    for (int k4 = 0; k4 < F_IN / 4; ++k4) {
        float4 hv[4];
#pragma unroll
        for (int rr = 0; rr < 4; ++rr)
            hv[rr] = hs4[(lr0 + rr) * (F_IN / 4) + k4];
#pragma unroll
        for (int kk = 0; kk < 4; ++kk) {
            float wv = Ws[(k4 * 4 + kk) * F_OUT + lane];
#pragma unroll
            for (int rr = 0; rr < 4; ++rr)
                acc[rr] += ((const float*)&hv[rr])[kk] * wv;
        }
    }

    const int b     = blockIdx.x >> 7;
    const int j0    = (blockIdx.x & 127) * 16;
    const size_t gr0 = (size_t)b * N + j0 + lr0;

#pragma unroll
    for (int rr = 0; rr < 4; ++rr) {
        t32[(lr0 + rr) * 65 + lane] = acc[rr];
        float fp = acc[rr] * av1;
        float gp = acc[rr] * av2;
#pragma unroll
        for (int off = 32; off >= 1; off >>= 1) {
            fp += __shfl_down(fp, off, 64);
            gp += __shfl_down(gp, off, 64);
        }
        if (lane == 0) {
            fv[gr0 + rr] = fp;
            gv[gr0 + rr] = gp;
        }
    }
    __syncthreads();

    const int f  = tid >> 2;
    const int jq = tid & 3;
    union { _Float16 h[4]; ushort4 u; } pk;
#pragma unroll
    for (int t = 0; t < 4; ++t)
        pk.h[t] = (_Float16)t32[(jq * 4 + t) * 65 + f];
    *(ushort4*)(WhT + (size_t)b * F_OUT * N + (size_t)f * N + j0 + jq * 4) = pk.u;
}

// ---------------------------------------------------------------------------
// Kernel 3: aggregation via MFMA, K=128 per barrier round (4 MFMA/wave/round).
// Block = (16 i's, batch b), 4 waves; wave w -> out[i0..15][16w..16w+15].
// Ps/WhTs stored as swizzled half8 slots: slot(r,pos) = r*16 + ((pos+r)&15).
// All four LDS access patterns hit exactly 8 lanes per 4-bank group (optimal).
// ---------------------------------------------------------------------------
__global__ __launch_bounds__(256) void attn_mfma_kernel(
    const _Float16* __restrict__ WhT, const float* __restrict__ fv,
    const float* __restrict__ gv, const unsigned* __restrict__ bits,
    float* __restrict__ out)
{
    const int i0 = blockIdx.x * 16;
    const int b  = blockIdx.y;
    const int tid  = threadIdx.x;
    const int lane = tid & 63;
    const int wsl  = tid >> 6;     // wave = feature slice

    __shared__ float    gs[N];              // 8 KB
    __shared__ float    fs[16];
    __shared__ unsigned mws[16 * 65];       // 4.16 KB, padded stride 65
    __shared__ half8    WhTs8[64 * 16];     // 16 KB, swizzled slots
    __shared__ half8    Ps8[16 * 16];       // 4 KB, swizzled slots
    __shared__ float    rs[16];
    __shared__ float    ms[16];

    // stage g row, f values, mask words (stride-65 padded)
    const float4* g4 = (const float4*)(gv + (size_t)b * N);
    ((float4*)gs)[tid]       = g4[tid];
    ((float4*)gs)[tid + 256] = g4[tid + 256];
    if (tid < 16) fs[tid] = fv[(size_t)b * N + i0 + tid];
    {
        uint4 mv = ((const uint4*)(bits + (size_t)i0 * 64))[tid];
        const int r = tid >> 4, c = tid & 15;
        mws[r * 65 + c * 4 + 0] = mv.x;
        mws[r * 65 + c * 4 + 1] = mv.y;
        mws[r * 65 + c * 4 + 2] = mv.z;
        mws[r * 65 + c * 4 + 3] = mv.w;
    }
    __syncthreads();

    const int ii = tid >> 4;        // i slot
    const int jj = tid & 15;        // j group

    // per-row masked max of g (leaky monotone => rowmax = leaky(fi + max g))
    float gmax = -INFINITY;
#pragma unroll
    for (int t = 0; t < 4; ++t) {
        unsigned mw = mws[ii * 65 + jj * 4 + t];
        const int jb = jj * 128 + t * 32;
        while (mw) {
            int bit = __builtin_ctz(mw);
            gmax = fmaxf(gmax, gs[jb + bit]);
            mw &= mw - 1;
        }
    }
#pragma unroll
    for (int off = 8; off >= 1; off >>= 1)
        gmax = fmaxf(gmax, __shfl_down(gmax, off, 16));
    if (jj == 0) {
        float m = fs[ii] + gmax;
        ms[ii] = (m > 0.f) ? m : ALPHA * m;
    }
    __syncthreads();

    const float fi = fs[ii];
    const float mi = ms[ii];
    const int fwh = tid >> 2;       // WhT row (feature) this thread stages
    const int seg = tid & 3;        // 32-f16 segment within row
    const _Float16* whbase = WhT + (size_t)b * F_OUT * N + (size_t)fwh * N;

    const int mrow = lane & 15;
    const int quad = lane >> 4;

    f32x4 acc = {0.f, 0.f, 0.f, 0.f};
    float psum = 0.f;

    for (int kt = 0; kt < N / 128; ++kt) {
        const int j0 = kt * 128;

        // global: 64x128 f16 slab, 4 half8 per thread
        half8 wv[4];
#pragma unroll
        for (int q = 0; q < 4; ++q)
            wv[q] = *(const half8*)(whbase + j0 + seg * 32 + q * 8);

        // P tile: 8 scores per thread (j = j0 + jj*8 .. +7), max-shifted
        const int jA = j0 + jj * 8;
        unsigned mbits = (mws[ii * 65 + (j0 >> 5) + (jj >> 2)] >> ((jj & 3) * 8)) & 0xFFu;
        half8 pk;
#pragma unroll
        for (int t = 0; t < 8; ++t) {
            float s = fi + gs[jA + t];
            s = (s > 0.f) ? s : ALPHA * s;
            float p = ((mbits >> t) & 1u) ? __expf(s - mi) : 0.f;
            pk[t] = (_Float16)p;
            psum += (float)pk[t];
        }
        Ps8[ii * 16 + ((jj + ii) & 15)] = pk;          // swizzled slot write
#pragma unroll
        for (int q = 0; q < 4; ++q)
            WhTs8[fwh * 16 + ((seg * 4 + q + fwh) & 15)] = wv[q];
        __syncthreads();

#pragma unroll
        for (int q = 0; q < 4; ++q) {
            half8 aF = Ps8[mrow * 16 + ((q * 4 + quad + mrow) & 15)];
            const int br = wsl * 16 + mrow;
            half8 bF = WhTs8[br * 16 + ((q * 4 + quad + br) & 15)];
            acc = __builtin_amdgcn_mfma_f32_16x16x32_f16(aF, bF, acc, 0, 0, 0);
        }
        __syncthreads();
    }

    // denominator: reduce psum over the 16 threads sharing ii
#pragma unroll
    for (int off = 8; off >= 1; off >>= 1)
        psum += __shfl_down(psum, off, 16);
    if (jj == 0) rs[ii] = psum;
    __syncthreads();

    // epilogue: D row = quad*4+reg, col = mrow
#pragma unroll
    for (int reg = 0; reg < 4; ++reg) {
        int irow = quad * 4 + reg;
        float v = acc[reg] / rs[irow];
        out[((size_t)b * N + i0 + irow) * F_OUT + wsl * 16 + mrow] = v;
    }
}

extern "C" void kernel_launch(void* const* d_in, const int* in_sizes, int n_in,
                              void* d_out, int out_size, void* d_ws, size_t ws_size,
                              hipStream_t stream) {
    const float* h   = (const float*)d_in[0];
    const float* adj = (const float*)d_in[1];
    const float* W   = (const float*)d_in[2];
    const float* a   = (const float*)d_in[3];
    float* out = (float*)d_out;

    char* ws = (char*)d_ws;
    _Float16* WhT = (_Float16*)ws;                        // 2 MB
    float* fv = (float*)(ws + (size_t)B * F_OUT * N * 2); // 64 KB
    float* gv = fv + (size_t)B * N;                       // 64 KB
    unsigned* bits = (unsigned*)(gv + (size_t)B * N);     // 512 KB

    bitmask_kernel<<<dim3(N), 256, 0, stream>>>(adj, bits);
    wh_fg_t_kernel<<<dim3(B * N / 16), 256, 0, stream>>>(h, W, a, WhT, fv, gv);
    attn_mfma_kernel<<<dim3(N / 16, B), 256, 0, stream>>>(WhT, fv, gv, bits, out);
}

// Round 10
// 134.519 us; speedup vs baseline: 1.1711x; 1.0881x over previous
//
#include <hip/hip_runtime.h>
#include <hip/hip_bf16.h>
#include <math.h>

#define B 8
#define N 2048
#define F_IN 128
#define F_OUT 64
#define ALPHA 0.2f

typedef _Float16 half8 __attribute__((ext_vector_type(8)));
typedef float f32x4 __attribute__((ext_vector_type(4)));

// ---------------------------------------------------------------------------
// Kernel 1: adj -> bitmask (u32 words). bits[i*64 + j/32] bit (j%32) = adj[i][j]>0
// ---------------------------------------------------------------------------
__global__ __launch_bounds__(256) void bitmask_kernel(
    const float* __restrict__ adj, unsigned* __restrict__ bits)
{
    const int i = blockIdx.x;
    const int tid = threadIdx.x;
    const int lane = tid & 63;
    const int w = tid >> 6;
    const float* row = adj + (size_t)i * N;
#pragma unroll
    for (int jt = 0; jt < 8; ++jt) {
        float v = row[jt * 256 + tid];
        unsigned long long m = __ballot(v > 0.f);
        if (lane == 0) {
            bits[i * 64 + jt * 8 + w * 2]     = (unsigned)m;
            bits[i * 64 + jt * 8 + w * 2 + 1] = (unsigned)(m >> 32);
        }
    }
}

// ---------------------------------------------------------------------------
// Kernel 2: WhT[b][f][j] (f16) = (h @ W)^T, plus f = Wh.a1, g = Wh.a2 (fp32)
// ---------------------------------------------------------------------------
__global__ __launch_bounds__(256) void wh_fg_t_kernel(
    const float* __restrict__ h, const float* __restrict__ W,
    const float* __restrict__ a, _Float16* __restrict__ WhT,
    float* __restrict__ fv, float* __restrict__ gv)
{
    const int tid  = threadIdx.x;
    const int w    = tid >> 6;
    const int lane = tid & 63;

    __shared__ float Ws[F_IN * F_OUT];    // 32 KB
    __shared__ float hs[16 * F_IN];       // 8 KB
    __shared__ float t32[16 * 65];        // transpose buffer (pad 65)

    const float4* W4 = (const float4*)W;
    float4* Ws4 = (float4*)Ws;
#pragma unroll
    for (int q = 0; q < 8; ++q)
        Ws4[q * 256 + tid] = W4[q * 256 + tid];

    const float4* h4 = (const float4*)h;
    float4* hs4 = (float4*)hs;
    const size_t hbase = (size_t)blockIdx.x * 512;
#pragma unroll
    for (int q = 0; q < 2; ++q)
        hs4[q * 256 + tid] = h4[hbase + q * 256 + tid];

    const float av1 = a[lane];
    const float av2 = a[F_OUT + lane];
    __syncthreads();

    float acc[4] = {0.f, 0.f, 0.f, 0.f};
    const int lr0 = w * 4;
    for (int k4 = 0; k4 < F_IN / 4; ++k4) {
        float4 hv[4];
#pragma unroll
        for (int rr = 0; rr < 4; ++rr)
            hv[rr] = hs4[(lr0 + rr) * (F_IN / 4) + k4];
#pragma unroll
        for (int kk = 0; kk < 4; ++kk) {
            float wv = Ws[(k4 * 4 + kk) * F_OUT + lane];
#pragma unroll
            for (int rr = 0; rr < 4; ++rr)
                acc[rr] += ((const float*)&hv[rr])[kk] * wv;
        }
    }

    const int b     = blockIdx.x >> 7;
    const int j0    = (blockIdx.x & 127) * 16;
    const size_t gr0 = (size_t)b * N + j0 + lr0;

#pragma unroll
    for (int rr = 0; rr < 4; ++rr) {
        t32[(lr0 + rr) * 65 + lane] = acc[rr];
        float fp = acc[rr] * av1;
        float gp = acc[rr] * av2;
#pragma unroll
        for (int off = 32; off >= 1; off >>= 1) {
            fp += __shfl_down(fp, off, 64);
            gp += __shfl_down(gp, off, 64);
        }
        if (lane == 0) {
            fv[gr0 + rr] = fp;
            gv[gr0 + rr] = gp;
        }
    }
    __syncthreads();

    const int f  = tid >> 2;
    const int jq = tid & 3;
    union { _Float16 h[4]; ushort4 u; } pk;
#pragma unroll
    for (int t = 0; t < 4; ++t)
        pk.h[t] = (_Float16)t32[(jq * 4 + t) * 65 + f];
    *(ushort4*)(WhT + (size_t)b * F_OUT * N + (size_t)f * N + j0 + jq * 4) = pk.u;
}

// ---------------------------------------------------------------------------
// Kernel 3: MFMA aggregation. Block = (16 i's, b), 4 waves = 4 feature slices.
// P computed once per block into double-buffered LDS (1 barrier/round);
// B-fragments register-prefetched one round ahead straight from L2-resident
// WhT (no LDS slab). A-reads use the rotated-slot layout (b128 floor).
// ---------------------------------------------------------------------------
__global__ __launch_bounds__(256) void attn_mfma_kernel(
    const _Float16* __restrict__ WhT, const float* __restrict__ fv,
    const float* __restrict__ gv, const unsigned* __restrict__ bits,
    float* __restrict__ out)
{
    const int i0 = blockIdx.x * 16;
    const int b  = blockIdx.y;
    const int tid  = threadIdx.x;
    const int lane = tid & 63;
    const int wsl  = tid >> 6;     // wave = feature slice

    __shared__ float    gs[N];              // 8 KB
    __shared__ float    fs[16];
    __shared__ unsigned mws[16 * 65];       // 4.16 KB, padded stride 65
    __shared__ half8    Ps8[2][16 * 16];    // 8 KB, double-buffered rotated slots
    __shared__ float    rs[16];
    __shared__ float    ms[16];

    // stage g row, f values, mask words (stride-65 padded)
    const float4* g4 = (const float4*)(gv + (size_t)b * N);
    ((float4*)gs)[tid]       = g4[tid];
    ((float4*)gs)[tid + 256] = g4[tid + 256];
    if (tid < 16) fs[tid] = fv[(size_t)b * N + i0 + tid];
    {
        uint4 mv = ((const uint4*)(bits + (size_t)i0 * 64))[tid];
        const int r = tid >> 4, c = tid & 15;
        mws[r * 65 + c * 4 + 0] = mv.x;
        mws[r * 65 + c * 4 + 1] = mv.y;
        mws[r * 65 + c * 4 + 2] = mv.z;
        mws[r * 65 + c * 4 + 3] = mv.w;
    }
    __syncthreads();

    const int ii = tid >> 4;        // i slot
    const int jj = tid & 15;        // j group

    // per-row masked max of g (leaky monotone => rowmax = leaky(fi + max g))
    float gmax = -INFINITY;
#pragma unroll
    for (int t = 0; t < 4; ++t) {
        unsigned mw = mws[ii * 65 + jj * 4 + t];
        const int jb = jj * 128 + t * 32;
        while (mw) {
            int bit = __builtin_ctz(mw);
            gmax = fmaxf(gmax, gs[jb + bit]);
            mw &= mw - 1;
        }
    }
#pragma unroll
    for (int off = 8; off >= 1; off >>= 1)
        gmax = fmaxf(gmax, __shfl_down(gmax, off, 16));
    if (jj == 0) {
        float m = fs[ii] + gmax;
        ms[ii] = (m > 0.f) ? m : ALPHA * m;
    }
    __syncthreads();

    const float fi = fs[ii];
    const float mi = ms[ii];
    const int mrow = lane & 15;
    const int quad = lane >> 4;
    // B-fragment source: feature row wsl*16+mrow, k-offset quad*8 (R6-proven)
    const _Float16* brow =
        WhT + ((size_t)b * F_OUT + wsl * 16 + mrow) * N + quad * 8;

    f32x4 acc = {0.f, 0.f, 0.f, 0.f};
    float psum = 0.f;
    half8 bcur[4], bnxt[4], pk;

    // P-gen for round kt: thread (ii,jj) -> 8 scores at j = kt*128 + jj*8
    auto genP = [&](int kt, half8& o8) {
        const int jA = kt * 128 + jj * 8;
        unsigned mbits = (mws[ii * 65 + kt * 4 + (jj >> 2)] >> ((jj & 3) * 8)) & 0xFFu;
        union { float4 v[2]; float s[8]; } gg;
        gg.v[0] = *(const float4*)(&gs[jA]);
        gg.v[1] = *(const float4*)(&gs[jA + 4]);
#pragma unroll
        for (int t = 0; t < 8; ++t) {
            float s = fi + gg.s[t];
            s = (s > 0.f) ? s : ALPHA * s;
            float p = ((mbits >> t) & 1u) ? __expf(s - mi) : 0.f;
            o8[t] = (_Float16)p;
            psum += (float)o8[t];
        }
    };

    // prefetch round 0
#pragma unroll
    for (int q = 0; q < 4; ++q)
        bcur[q] = *(const half8*)(brow + q * 32);
    genP(0, pk);

    for (int kt = 0; kt < N / 128; ++kt) {
        const int buf = kt & 1;
        Ps8[buf][ii * 16 + ((jj + ii) & 15)] = pk;   // rotated slot write
        __syncthreads();                              // Ps[buf] ready

        if (kt < N / 128 - 1) {
#pragma unroll
            for (int q = 0; q < 4; ++q)               // prefetch next round's B
                bnxt[q] = *(const half8*)(brow + (kt + 1) * 128 + q * 32);
        }

#pragma unroll
        for (int q = 0; q < 4; ++q) {
            half8 aF = Ps8[buf][mrow * 16 + ((q * 4 + quad + mrow) & 15)];
            acc = __builtin_amdgcn_mfma_f32_16x16x32_f16(aF, bcur[q], acc, 0, 0, 0);
        }

        if (kt < N / 128 - 1) {
            genP(kt + 1, pk);                         // VALU overlaps MFMA
#pragma unroll
            for (int q = 0; q < 4; ++q)
                bcur[q] = bnxt[q];
        }
    }

    // denominator: reduce psum over the 16 threads sharing ii
#pragma unroll
    for (int off = 8; off >= 1; off >>= 1)
        psum += __shfl_down(psum, off, 16);
    if (jj == 0) rs[ii] = psum;
    __syncthreads();

    // epilogue: D row = quad*4+reg, col = mrow
#pragma unroll
    for (int reg = 0; reg < 4; ++reg) {
        int irow = quad * 4 + reg;
        float v = acc[reg] / rs[irow];
        out[((size_t)b * N + i0 + irow) * F_OUT + wsl * 16 + mrow] = v;
    }
}

extern "C" void kernel_launch(void* const* d_in, const int* in_sizes, int n_in,
                              void* d_out, int out_size, void* d_ws, size_t ws_size,
                              hipStream_t stream) {
    const float* h   = (const float*)d_in[0];
    const float* adj = (const float*)d_in[1];
    const float* W   = (const float*)d_in[2];
    const float* a   = (const float*)d_in[3];
    float* out = (float*)d_out;

    char* ws = (char*)d_ws;
    _Float16* WhT = (_Float16*)ws;                        // 2 MB
    float* fv = (float*)(ws + (size_t)B * F_OUT * N * 2); // 64 KB
    float* gv = fv + (size_t)B * N;                       // 64 KB
    unsigned* bits = (unsigned*)(gv + (size_t)B * N);     // 512 KB

    bitmask_kernel<<<dim3(N), 256, 0, stream>>>(adj, bits);
    wh_fg_t_kernel<<<dim3(B * N / 16), 256, 0, stream>>>(h, W, a, WhT, fv, gv);
    attn_mfma_kernel<<<dim3(N / 16, B), 256, 0, stream>>>(WhT, fv, gv, bits, out);
}